// Round 10
// baseline (257.425 us; speedup 1.0000x reference)
//
#include <hip/hip_runtime.h>
#include <hip/hip_bf16.h>

#define EPS  1e-5f
#define SPAN 400          // dst nodes per bin
#define MAXB 256          // max bins (N <= 102400)
#define PBE  2048         // edges per k_pairs block
typedef __hip_bfloat16 bf16;
typedef int iv4 __attribute__((ext_vector_type(4)));
typedef int iv2 __attribute__((ext_vector_type(2)));

__device__ __forceinline__ float bflo(unsigned u) { return __uint_as_float(u << 16); }
__device__ __forceinline__ float bfhi(unsigned u) { return __uint_as_float(u & 0xffff0000u); }

// ---------------------------------------------------------------------------
// Pass 1: bin histogram of dst (bin = d/SPAN). Edge stream nt, read once.
// ---------------------------------------------------------------------------
__global__ void k_hist(const int* __restrict__ dst, int* __restrict__ binCnt, int nE)
{
    __shared__ int hist[MAXB];
    int t = threadIdx.x;
    for (int k = t; k < MAXB; k += blockDim.x) hist[k] = 0;
    __syncthreads();
    int tid = blockIdx.x * blockDim.x + t;
    int stride = gridDim.x * blockDim.x;
    const iv4* d4 = (const iv4*)dst;
    int n4 = nE >> 2;
    for (int e = tid; e < n4; e += stride) {
        iv4 d = __builtin_nontemporal_load(&d4[e]);
        atomicAdd(&hist[d.x / SPAN], 1);
        atomicAdd(&hist[d.y / SPAN], 1);
        atomicAdd(&hist[d.z / SPAN], 1);
        atomicAdd(&hist[d.w / SPAN], 1);
    }
    if (blockIdx.x == 0 && t == 0)
        for (int e = n4 << 2; e < nE; ++e) atomicAdd(&hist[dst[e] / SPAN], 1);
    __syncthreads();
    for (int k = t; k < MAXB; k += blockDim.x)
        if (hist[k]) atomicAdd(&binCnt[k], hist[k]);
}

// ---------------------------------------------------------------------------
// Exclusive scan of bin counts (one 256-thread block)
// ---------------------------------------------------------------------------
__global__ void k_binscan(const int* __restrict__ binCnt, int* __restrict__ binStart,
                          int* __restrict__ binCur, int nbins, int nE)
{
    __shared__ int ls[MAXB];
    int t = threadIdx.x;
    ls[t] = (t < nbins) ? binCnt[t] : 0;
    __syncthreads();
#pragma unroll
    for (int off = 1; off < MAXB; off <<= 1) {
        int u = (t >= off) ? ls[t - off] : 0;
        __syncthreads();
        ls[t] += u;
        __syncthreads();
    }
    int start = (t == 0) ? 0 : ls[t - 1];
    if (t < nbins) { binStart[t] = start; binCur[t] = start; }
    if (t == 0) binStart[nbins] = nE;
}

// ---------------------------------------------------------------------------
// Pass 2: partition (dst,src) pairs into bin-contiguous staging.
// ---------------------------------------------------------------------------
__global__ void k_pairs(const int* __restrict__ src, const int* __restrict__ dst,
                        int* __restrict__ binCur, iv2* __restrict__ stg, int nE)
{
    __shared__ int hist[MAXB], base[MAXB], cur[MAXB];
    int t = threadIdx.x;
    for (int k = t; k < MAXB; k += 256) { hist[k] = 0; cur[k] = 0; }
    __syncthreads();
    const iv4* d4 = (const iv4*)dst;
    const iv4* s4 = (const iv4*)src;
    int n4 = nE >> 2;
    int i0 = blockIdx.x * (PBE / 4) + 2 * t;
    bool v0 = i0 < n4, v1 = i0 + 1 < n4;
    iv4 d0 = {0,0,0,0}, s0 = {0,0,0,0}, d1 = {0,0,0,0}, s1 = {0,0,0,0};
    if (v0) { d0 = __builtin_nontemporal_load(&d4[i0]);     s0 = __builtin_nontemporal_load(&s4[i0]); }
    if (v1) { d1 = __builtin_nontemporal_load(&d4[i0 + 1]); s1 = __builtin_nontemporal_load(&s4[i0 + 1]); }
    if (v0) {
        atomicAdd(&hist[d0.x / SPAN], 1); atomicAdd(&hist[d0.y / SPAN], 1);
        atomicAdd(&hist[d0.z / SPAN], 1); atomicAdd(&hist[d0.w / SPAN], 1);
    }
    if (v1) {
        atomicAdd(&hist[d1.x / SPAN], 1); atomicAdd(&hist[d1.y / SPAN], 1);
        atomicAdd(&hist[d1.z / SPAN], 1); atomicAdd(&hist[d1.w / SPAN], 1);
    }
    bool tailblk = (blockIdx.x == gridDim.x - 1) && (t == 0);
    if (tailblk)
        for (int e = n4 << 2; e < nE; ++e) atomicAdd(&hist[dst[e] / SPAN], 1);
    __syncthreads();
    for (int k = t; k < MAXB; k += 256) {
        int tot = hist[k];
        base[k] = tot ? atomicAdd(&binCur[k], tot) : 0;
    }
    __syncthreads();
#define EMIT(dd, ss_) { int b = (dd) / SPAN; \
        int p = base[b] + atomicAdd(&cur[b], 1); \
        iv2 pr; pr.x = (dd); pr.y = (ss_); stg[p] = pr; }
    if (v0) { EMIT(d0.x, s0.x) EMIT(d0.y, s0.y) EMIT(d0.z, s0.z) EMIT(d0.w, s0.w) }
    if (v1) { EMIT(d1.x, s1.x) EMIT(d1.y, s1.y) EMIT(d1.z, s1.z) EMIT(d1.w, s1.w) }
    if (tailblk)
        for (int e = n4 << 2; e < nE; ++e) { EMIT(dst[e], src[e]) }
#undef EMIT
}

// ---------------------------------------------------------------------------
// Pass 3: per-bin LDS counting sort -> rp, inv_cnt, csr.
// ---------------------------------------------------------------------------
__global__ __launch_bounds__(1024) void k_sortbin(
    const iv2* __restrict__ stg, const int* __restrict__ binStart,
    int* __restrict__ rp, float* __restrict__ inv_cnt, int* __restrict__ csr,
    int n, int nbins)
{
    __shared__ int cnt[SPAN];
    __shared__ int cur[SPAN];
    __shared__ int ls[512];
    int t = threadIdx.x;
    int bin = blockIdx.x, lo = bin * SPAN;
    int nn = min(SPAN, n - lo);
    for (int k = t; k < SPAN; k += 1024) cnt[k] = 0;
    __syncthreads();
    int e0 = binStart[bin], e1 = binStart[bin + 1];
    for (int e = e0 + t; e < e1; e += 1024) {
        iv2 p = __builtin_nontemporal_load(&stg[e]);
        atomicAdd(&cnt[p.x - lo], 1);
    }
    __syncthreads();
    if (t < 512) ls[t] = (t < nn) ? cnt[t] : 0;
    __syncthreads();
#pragma unroll
    for (int off = 1; off < 512; off <<= 1) {
        int u = (t >= off && t < 512) ? ls[t - off] : 0;
        __syncthreads();
        if (t < 512) ls[t] += u;
        __syncthreads();
    }
    if (t < nn) {
        int c = cnt[t];
        int excl = ls[t] - c;
        cur[t] = excl;
        rp[lo + t] = e0 + excl;
        inv_cnt[lo + t] = 1.0f / fmaxf((float)c, 1.0f);
    }
    if (bin == nbins - 1 && t == 0) rp[n] = e1;
    __syncthreads();
    for (int e = e0 + t; e < e1; e += 1024) {
        iv2 p = __builtin_nontemporal_load(&stg[e]);
        int pos = atomicAdd(&cur[p.x - lo], 1);
        csr[e0 + pos] = p.y;
    }
}

// ---------------------------------------------------------------------------
// Layer 1: 16 lanes per node; shfl-reduce; BN+ReLU fused; bf16 out.
// ---------------------------------------------------------------------------
__global__ void k_l1g(const int* __restrict__ rp, const int* __restrict__ csr,
                      const float* __restrict__ inv_cnt, const float* __restrict__ x,
                      const float* __restrict__ W1l, const float* __restrict__ b1l,
                      const float* __restrict__ W1r,
                      const float* __restrict__ gam, const float* __restrict__ bet,
                      const float* __restrict__ mu,  const float* __restrict__ var,
                      bf16* __restrict__ hout, int n)
{
    __shared__ float sWl[16], sb[16], sWr[16], ssc[16], sbi[16];
    int t = threadIdx.x;
    if (t < 16) {
        sWl[t] = W1l[t]; sb[t] = b1l[t]; sWr[t] = W1r[t];
        float sc = gam[t] * rsqrtf(var[t] + EPS);
        ssc[t] = sc;
        sbi[t] = bet[t] - mu[t] * sc;
    }
    __syncthreads();
    int grp = t >> 4, f = t & 15;
    int i = blockIdx.x * 16 + grp;
    if (i >= n) return;
    int r0 = rp[i], r1 = rp[i + 1];
    float s = 0.0f;
    for (int k = r0 + f; k < r1; k += 16) s += x[csr[k]];
#pragma unroll
    for (int m = 8; m >= 1; m >>= 1) s += __shfl_xor(s, m, 64);
    float mean = s * inv_cnt[i];
    float xv = x[i];
    float v = fmaf(mean, sWl[f], sb[f]);
    v = fmaf(xv, sWr[f], v);
    v = fmaxf(fmaf(v, ssc[f], sbi[f]), 0.0f);
    hout[(size_t)i * 16 + f] = __float2bfloat16(v);
}

// ---------------------------------------------------------------------------
// Layers 2,3: gather-mean with 4B/lane loads (8 lanes cover a 32B row,
// 2 neighbors in flight per 16-lane group) + 16->16 transform + ReLU.
// ---------------------------------------------------------------------------
__global__ void k_sage16(const int* __restrict__ rp, const int* __restrict__ csr,
                         const float* __restrict__ inv_cnt, const bf16* __restrict__ h,
                         const float* __restrict__ Wl, const float* __restrict__ bl,
                         const float* __restrict__ Wr,
                         bf16* __restrict__ hout, int n)
{
    __shared__ float sWlT[256], sWrT[256], sb[16];
    __shared__ float sA[16][17], sX[16][17];
    int t = threadIdx.x;
    {
        int j = t & 15, ii = t >> 4;
        sWlT[ii * 16 + j] = Wl[j * 16 + ii];   // LDS addr = t: linear, conflict-free
        sWrT[ii * 16 + j] = Wr[j * 16 + ii];
    }
    if (t < 16) sb[t] = bl[t];
    int grp = t >> 4, f = t & 15;
    int half = (t >> 3) & 1, s2 = t & 7;
    int i = blockIdx.x * 16 + grp;
    bool valid = i < n;
    const unsigned short* hu = (const unsigned short*)h;
    float a0 = 0.0f, a1 = 0.0f;
    if (valid) {
        int r0 = rp[i], r1 = rp[i + 1];
#pragma unroll 2
        for (int k = r0 + half; k < r1; k += 2) {
            int nb = csr[k];
            unsigned u = *(const unsigned*)(hu + (size_t)nb * 16 + s2 * 2);
            a0 += bflo(u);
            a1 += bfhi(u);
        }
    }
    a0 += __shfl_xor(a0, 8, 64);
    a1 += __shfl_xor(a1, 8, 64);
    if (valid && half == 0) {
        float ic = inv_cnt[i];
        sA[grp][2 * s2]     = a0 * ic;
        sA[grp][2 * s2 + 1] = a1 * ic;
        unsigned u = *(const unsigned*)(hu + (size_t)i * 16 + s2 * 2);
        sX[grp][2 * s2]     = bflo(u);
        sX[grp][2 * s2 + 1] = bfhi(u);
    }
    __syncthreads();
    if (valid) {
        float o = sb[f];
#pragma unroll
        for (int ii = 0; ii < 16; ++ii) {
            o = fmaf(sA[grp][ii], sWlT[ii * 16 + f], o);
            o = fmaf(sX[grp][ii], sWrT[ii * 16 + f], o);
        }
        hout[(size_t)i * 16 + f] = __float2bfloat16(fmaxf(o, 0.0f));
    }
}

// ---------------------------------------------------------------------------
// Layer 4 + decoder + softmax, fused with gather.
// Weight staging: LDS-linear writes (conflict-free), global-transposed reads.
// ---------------------------------------------------------------------------
__global__ void k_fin(const int* __restrict__ rp, const int* __restrict__ csr,
                      const float* __restrict__ inv_cnt, const bf16* __restrict__ h,
                      const float* __restrict__ W4l, const float* __restrict__ b4l,
                      const float* __restrict__ W4r,
                      const float* __restrict__ Wd1, const float* __restrict__ bd1,
                      const float* __restrict__ Wd2, const float* __restrict__ bd2,
                      float* __restrict__ out, int n)
{
    __shared__ float sW4lT[512], sW4rT[512], sb4[32];
    __shared__ float sWd1T[1024], sbd1[32], sWd2[64], sbd2[2];
    __shared__ float sA[16][17], sX[16][17], sH4[16][33];
    int t = threadIdx.x;
    for (int k = t; k < 512; k += 256) {       // sW4lT[ii*32+j] = W4l[j*16+ii]
        int ii = k >> 5, j = k & 31;
        sW4lT[k] = W4l[j * 16 + ii];
        sW4rT[k] = W4r[j * 16 + ii];
    }
    for (int k = t; k < 1024; k += 256) {      // sWd1T[ii*32+j] = Wd1[j*32+ii]
        int ii = k >> 5, j = k & 31;
        sWd1T[k] = Wd1[j * 32 + ii];
    }
    if (t < 32) { sb4[t] = b4l[t]; sbd1[t] = bd1[t]; }
    if (t < 64) sWd2[t] = Wd2[t];
    if (t < 2)  sbd2[t] = bd2[t];
    int grp = t >> 4, f = t & 15;
    int half = (t >> 3) & 1, s2 = t & 7;
    int i = blockIdx.x * 16 + grp;
    bool valid = i < n;
    const unsigned short* hu = (const unsigned short*)h;
    float a0 = 0.0f, a1 = 0.0f;
    if (valid) {
        int r0 = rp[i], r1 = rp[i + 1];
#pragma unroll 2
        for (int k = r0 + half; k < r1; k += 2) {
            int nb = csr[k];
            unsigned u = *(const unsigned*)(hu + (size_t)nb * 16 + s2 * 2);
            a0 += bflo(u);
            a1 += bfhi(u);
        }
    }
    a0 += __shfl_xor(a0, 8, 64);
    a1 += __shfl_xor(a1, 8, 64);
    if (valid && half == 0) {
        float ic = inv_cnt[i];
        sA[grp][2 * s2]     = a0 * ic;
        sA[grp][2 * s2 + 1] = a1 * ic;
        unsigned u = *(const unsigned*)(hu + (size_t)i * 16 + s2 * 2);
        sX[grp][2 * s2]     = bflo(u);
        sX[grp][2 * s2 + 1] = bfhi(u);
    }
    __syncthreads();
    float h4a = sb4[f], h4b = sb4[f + 16];
#pragma unroll
    for (int ii = 0; ii < 16; ++ii) {
        float a  = sA[grp][ii];
        float xx = sX[grp][ii];
        h4a = fmaf(a,  sW4lT[ii * 32 + f],      h4a);
        h4b = fmaf(a,  sW4lT[ii * 32 + f + 16], h4b);
        h4a = fmaf(xx, sW4rT[ii * 32 + f],      h4a);
        h4b = fmaf(xx, sW4rT[ii * 32 + f + 16], h4b);
    }
    sH4[grp][f] = h4a;
    sH4[grp][f + 16] = h4b;
    __syncthreads();
    float za = sbd1[f], zb = sbd1[f + 16];
#pragma unroll
    for (int k = 0; k < 32; ++k) {
        float hv = sH4[grp][k];
        za = fmaf(hv, sWd1T[k * 32 + f],      za);
        zb = fmaf(hv, sWd1T[k * 32 + f + 16], zb);
    }
    za = fmaxf(za, 0.0f);
    zb = fmaxf(zb, 0.0f);
    float o0 = za * sWd2[f]      + zb * sWd2[f + 16];
    float o1 = za * sWd2[32 + f] + zb * sWd2[32 + f + 16];
#pragma unroll
    for (int m = 8; m >= 1; m >>= 1) {
        o0 += __shfl_xor(o0, m, 64);
        o1 += __shfl_xor(o1, m, 64);
    }
    if (valid && f == 0) {
        o0 += sbd2[0]; o1 += sbd2[1];
        float mx = fmaxf(o0, o1);
        float e0 = expf(o0 - mx), e1 = expf(o1 - mx);
        float inv = 1.0f / (e0 + e1);
        out[(size_t)2 * i + 0] = e0 * inv;
        out[(size_t)2 * i + 1] = e1 * inv;
    }
}

// ---------------------------------------------------------------------------
extern "C" void kernel_launch(void* const* d_in, const int* in_sizes, int n_in,
                              void* d_out, int out_size, void* d_ws, size_t ws_size,
                              hipStream_t stream)
{
    const float* x  = (const float*)d_in[0];
    const int*   ei = (const int*)d_in[1];
    const int    N  = in_sizes[0];
    const int    E  = in_sizes[1] / 2;
    const int* src = ei;
    const int* dst = ei + E;

    const float* W1l = (const float*)d_in[2];
    const float* b1l = (const float*)d_in[3];
    const float* W1r = (const float*)d_in[4];
    const float* gam = (const float*)d_in[5];
    const float* bet = (const float*)d_in[6];
    const float* mu  = (const float*)d_in[7];
    const float* var = (const float*)d_in[8];
    const float* W2l = (const float*)d_in[9];
    const float* b2l = (const float*)d_in[10];
    const float* W2r = (const float*)d_in[11];
    const float* W3l = (const float*)d_in[12];
    const float* b3l = (const float*)d_in[13];
    const float* W3r = (const float*)d_in[14];
    const float* W4l = (const float*)d_in[15];
    const float* b4l = (const float*)d_in[16];
    const float* W4r = (const float*)d_in[17];
    const float* Wd1 = (const float*)d_in[18];
    const float* bd1 = (const float*)d_in[19];
    const float* Wd2 = (const float*)d_in[20];
    const float* bd2 = (const float*)d_in[21];

    char*  base = (char*)d_ws;
    size_t off  = 0;
    auto alloc = [&](size_t bytes) { size_t p = off; off += (bytes + 63) & ~(size_t)63; return p; };
    float* inv_cnt  = (float*)(base + alloc((size_t)N * 4));
    int*   rp       = (int*)  (base + alloc((size_t)(N + 1) * 4));
    int*   binCnt   = (int*)  (base + alloc(MAXB * 4));
    int*   binStart = (int*)  (base + alloc((MAXB + 1) * 4));
    int*   binCur   = (int*)  (base + alloc(MAXB * 4));
    int*   csr      = (int*)  (base + alloc((size_t)E * 4));
    // stg aliases hA/hB region: stg dead after k_sortbin, hA first written in k_l1g
    size_t regionOff = alloc((size_t)E * 8 > (size_t)N * 64 ? (size_t)E * 8 : (size_t)N * 64);
    iv2*   stg = (iv2*) (base + regionOff);
    bf16*  hA  = (bf16*)(base + regionOff);
    bf16*  hB  = hA + (size_t)N * 16;
    (void)ws_size;

    int nbins   = (N + SPAN - 1) / SPAN;
    int nbPairs = (E + PBE - 1) / PBE;
    int nbN16   = (N + 15) / 16;

    // --- partition edges by dst bin, then per-bin counting sort -> CSR ---
    hipMemsetAsync(binCnt, 0, MAXB * sizeof(int), stream);
    k_hist<<<1024, 256, 0, stream>>>(dst, binCnt, E);
    k_binscan<<<1, 256, 0, stream>>>(binCnt, binStart, binCur, nbins, E);
    k_pairs<<<nbPairs, 256, 0, stream>>>(src, dst, binCur, stg, E);
    k_sortbin<<<nbins, 1024, 0, stream>>>(stg, binStart, rp, inv_cnt, csr, N, nbins);

    // --- gather-based layers ---
    k_l1g<<<nbN16, 256, 0, stream>>>(rp, csr, inv_cnt, x, W1l, b1l, W1r,
                                     gam, bet, mu, var, hA, N);
    k_sage16<<<nbN16, 256, 0, stream>>>(rp, csr, inv_cnt, hA, W2l, b2l, W2r, hB, N);
    k_sage16<<<nbN16, 256, 0, stream>>>(rp, csr, inv_cnt, hB, W3l, b3l, W3r, hA, N);
    k_fin<<<nbN16, 256, 0, stream>>>(rp, csr, inv_cnt, hA, W4l, b4l, W4r,
                                     Wd1, bd1, Wd2, bd2, (float*)d_out, N);
}

// Round 11
// 252.388 us; speedup vs baseline: 1.0200x; 1.0200x over previous
//
#include <hip/hip_runtime.h>
#include <hip/hip_bf16.h>

#define EPS  1e-5f
#define SPAN 400          // dst nodes per bin
#define MAXB 256          // max bins (N <= 102400)
#define PBE  2048         // edges per k_pairs block
typedef __hip_bfloat16 bf16;
typedef int iv4 __attribute__((ext_vector_type(4)));
typedef int iv2 __attribute__((ext_vector_type(2)));

__device__ __forceinline__ float bflo(unsigned u) { return __uint_as_float(u << 16); }
__device__ __forceinline__ float bfhi(unsigned u) { return __uint_as_float(u & 0xffff0000u); }

// ---------------------------------------------------------------------------
// Pass 1: bin histogram of dst (bin = d/SPAN). Edge stream nt, read once.
// ---------------------------------------------------------------------------
__global__ void k_hist(const int* __restrict__ dst, int* __restrict__ binCnt, int nE)
{
    __shared__ int hist[MAXB];
    int t = threadIdx.x;
    for (int k = t; k < MAXB; k += blockDim.x) hist[k] = 0;
    __syncthreads();
    int tid = blockIdx.x * blockDim.x + t;
    int stride = gridDim.x * blockDim.x;
    const iv4* d4 = (const iv4*)dst;
    int n4 = nE >> 2;
    for (int e = tid; e < n4; e += stride) {
        iv4 d = __builtin_nontemporal_load(&d4[e]);
        atomicAdd(&hist[d.x / SPAN], 1);
        atomicAdd(&hist[d.y / SPAN], 1);
        atomicAdd(&hist[d.z / SPAN], 1);
        atomicAdd(&hist[d.w / SPAN], 1);
    }
    if (blockIdx.x == 0 && t == 0)
        for (int e = n4 << 2; e < nE; ++e) atomicAdd(&hist[dst[e] / SPAN], 1);
    __syncthreads();
    for (int k = t; k < MAXB; k += blockDim.x)
        if (hist[k]) atomicAdd(&binCnt[k], hist[k]);
}

// ---------------------------------------------------------------------------
// Exclusive scan of bin counts (one 256-thread block)
// ---------------------------------------------------------------------------
__global__ void k_binscan(const int* __restrict__ binCnt, int* __restrict__ binStart,
                          int* __restrict__ binCur, int nbins, int nE)
{
    __shared__ int ls[MAXB];
    int t = threadIdx.x;
    ls[t] = (t < nbins) ? binCnt[t] : 0;
    __syncthreads();
#pragma unroll
    for (int off = 1; off < MAXB; off <<= 1) {
        int u = (t >= off) ? ls[t - off] : 0;
        __syncthreads();
        ls[t] += u;
        __syncthreads();
    }
    int start = (t == 0) ? 0 : ls[t - 1];
    if (t < nbins) { binStart[t] = start; binCur[t] = start; }
    if (t == 0) binStart[nbins] = nE;
}

// ---------------------------------------------------------------------------
// Pass 2: partition (dst,src) pairs into bin-contiguous staging.
// ---------------------------------------------------------------------------
__global__ void k_pairs(const int* __restrict__ src, const int* __restrict__ dst,
                        int* __restrict__ binCur, iv2* __restrict__ stg, int nE)
{
    __shared__ int hist[MAXB], base[MAXB], cur[MAXB];
    int t = threadIdx.x;
    for (int k = t; k < MAXB; k += 256) { hist[k] = 0; cur[k] = 0; }
    __syncthreads();
    const iv4* d4 = (const iv4*)dst;
    const iv4* s4 = (const iv4*)src;
    int n4 = nE >> 2;
    int i0 = blockIdx.x * (PBE / 4) + 2 * t;
    bool v0 = i0 < n4, v1 = i0 + 1 < n4;
    iv4 d0 = {0,0,0,0}, s0 = {0,0,0,0}, d1 = {0,0,0,0}, s1 = {0,0,0,0};
    if (v0) { d0 = __builtin_nontemporal_load(&d4[i0]);     s0 = __builtin_nontemporal_load(&s4[i0]); }
    if (v1) { d1 = __builtin_nontemporal_load(&d4[i0 + 1]); s1 = __builtin_nontemporal_load(&s4[i0 + 1]); }
    if (v0) {
        atomicAdd(&hist[d0.x / SPAN], 1); atomicAdd(&hist[d0.y / SPAN], 1);
        atomicAdd(&hist[d0.z / SPAN], 1); atomicAdd(&hist[d0.w / SPAN], 1);
    }
    if (v1) {
        atomicAdd(&hist[d1.x / SPAN], 1); atomicAdd(&hist[d1.y / SPAN], 1);
        atomicAdd(&hist[d1.z / SPAN], 1); atomicAdd(&hist[d1.w / SPAN], 1);
    }
    bool tailblk = (blockIdx.x == gridDim.x - 1) && (t == 0);
    if (tailblk)
        for (int e = n4 << 2; e < nE; ++e) atomicAdd(&hist[dst[e] / SPAN], 1);
    __syncthreads();
    for (int k = t; k < MAXB; k += 256) {
        int tot = hist[k];
        base[k] = tot ? atomicAdd(&binCur[k], tot) : 0;
    }
    __syncthreads();
#define EMIT(dd, ss_) { int b = (dd) / SPAN; \
        int p = base[b] + atomicAdd(&cur[b], 1); \
        iv2 pr; pr.x = (dd); pr.y = (ss_); stg[p] = pr; }
    if (v0) { EMIT(d0.x, s0.x) EMIT(d0.y, s0.y) EMIT(d0.z, s0.z) EMIT(d0.w, s0.w) }
    if (v1) { EMIT(d1.x, s1.x) EMIT(d1.y, s1.y) EMIT(d1.z, s1.z) EMIT(d1.w, s1.w) }
    if (tailblk)
        for (int e = n4 << 2; e < nE; ++e) { EMIT(dst[e], src[e]) }
#undef EMIT
}

// ---------------------------------------------------------------------------
// Pass 3: per-bin LDS counting sort -> rp, inv_cnt, csr.
// ---------------------------------------------------------------------------
__global__ __launch_bounds__(1024) void k_sortbin(
    const iv2* __restrict__ stg, const int* __restrict__ binStart,
    int* __restrict__ rp, float* __restrict__ inv_cnt, int* __restrict__ csr,
    int n, int nbins)
{
    __shared__ int cnt[SPAN];
    __shared__ int cur[SPAN];
    __shared__ int ls[512];
    int t = threadIdx.x;
    int bin = blockIdx.x, lo = bin * SPAN;
    int nn = min(SPAN, n - lo);
    for (int k = t; k < SPAN; k += 1024) cnt[k] = 0;
    __syncthreads();
    int e0 = binStart[bin], e1 = binStart[bin + 1];
    for (int e = e0 + t; e < e1; e += 1024) {
        iv2 p = __builtin_nontemporal_load(&stg[e]);
        atomicAdd(&cnt[p.x - lo], 1);
    }
    __syncthreads();
    if (t < 512) ls[t] = (t < nn) ? cnt[t] : 0;
    __syncthreads();
#pragma unroll
    for (int off = 1; off < 512; off <<= 1) {
        int u = (t >= off && t < 512) ? ls[t - off] : 0;
        __syncthreads();
        if (t < 512) ls[t] += u;
        __syncthreads();
    }
    if (t < nn) {
        int c = cnt[t];
        int excl = ls[t] - c;
        cur[t] = excl;
        rp[lo + t] = e0 + excl;
        inv_cnt[lo + t] = 1.0f / fmaxf((float)c, 1.0f);
    }
    if (bin == nbins - 1 && t == 0) rp[n] = e1;
    __syncthreads();
    for (int e = e0 + t; e < e1; e += 1024) {
        iv2 p = __builtin_nontemporal_load(&stg[e]);
        int pos = atomicAdd(&cur[p.x - lo], 1);
        csr[e0 + pos] = p.y;
    }
}

// ---------------------------------------------------------------------------
// Layer 1: 16 lanes per node; shfl-reduce; BN+ReLU fused; bf16 out.
// ---------------------------------------------------------------------------
__global__ void k_l1g(const int* __restrict__ rp, const int* __restrict__ csr,
                      const float* __restrict__ inv_cnt, const float* __restrict__ x,
                      const float* __restrict__ W1l, const float* __restrict__ b1l,
                      const float* __restrict__ W1r,
                      const float* __restrict__ gam, const float* __restrict__ bet,
                      const float* __restrict__ mu,  const float* __restrict__ var,
                      bf16* __restrict__ hout, int n)
{
    __shared__ float sWl[16], sb[16], sWr[16], ssc[16], sbi[16];
    int t = threadIdx.x;
    if (t < 16) {
        sWl[t] = W1l[t]; sb[t] = b1l[t]; sWr[t] = W1r[t];
        float sc = gam[t] * rsqrtf(var[t] + EPS);
        ssc[t] = sc;
        sbi[t] = bet[t] - mu[t] * sc;
    }
    __syncthreads();
    int grp = t >> 4, f = t & 15;
    int i = blockIdx.x * 16 + grp;
    if (i >= n) return;
    int r0 = rp[i], r1 = rp[i + 1];
    float s = 0.0f;
    for (int k = r0 + f; k < r1; k += 16) s += x[csr[k]];
#pragma unroll
    for (int m = 8; m >= 1; m >>= 1) s += __shfl_xor(s, m, 64);
    float mean = s * inv_cnt[i];
    float xv = x[i];
    float v = fmaf(mean, sWl[f], sb[f]);
    v = fmaf(xv, sWr[f], v);
    v = fmaxf(fmaf(v, ssc[f], sbi[f]), 0.0f);
    hout[(size_t)i * 16 + f] = __float2bfloat16(v);
}

// ---------------------------------------------------------------------------
// Wide gather: 16-lane group covers 8 neighbor rows per load instruction.
// Lane l: neighbor slot l>>1, half-row parity l&1, uint4 = 16B = 8 bf16.
// Reduce across 8 same-parity lanes via shfl_xor(2,4,8); lanes 0/1 write LDS.
// ---------------------------------------------------------------------------
__device__ __forceinline__ void gather8(const unsigned short* hu,
                                        const int* __restrict__ csr,
                                        int r0, int r1, bool valid,
                                        int sl, int pr, float ic,
                                        int lane16, float* sArow)
{
    float a0 = 0, a1 = 0, a2 = 0, a3 = 0, a4 = 0, a5 = 0, a6 = 0, a7 = 0;
    if (valid) {
        for (int k = r0 + sl; k < r1; k += 8) {
            int nb = csr[k];
            const uint4* rowp = (const uint4*)(hu + (size_t)nb * 16 + pr * 8);
            uint4 u = *rowp;
            a0 += bflo(u.x); a1 += bfhi(u.x);
            a2 += bflo(u.y); a3 += bfhi(u.y);
            a4 += bflo(u.z); a5 += bfhi(u.z);
            a6 += bflo(u.w); a7 += bfhi(u.w);
        }
    }
#pragma unroll
    for (int m = 2; m <= 8; m <<= 1) {
        a0 += __shfl_xor(a0, m, 64); a1 += __shfl_xor(a1, m, 64);
        a2 += __shfl_xor(a2, m, 64); a3 += __shfl_xor(a3, m, 64);
        a4 += __shfl_xor(a4, m, 64); a5 += __shfl_xor(a5, m, 64);
        a6 += __shfl_xor(a6, m, 64); a7 += __shfl_xor(a7, m, 64);
    }
    if (valid && lane16 < 2) {
        float* p = sArow + pr * 8;
        p[0] = a0 * ic; p[1] = a1 * ic; p[2] = a2 * ic; p[3] = a3 * ic;
        p[4] = a4 * ic; p[5] = a5 * ic; p[6] = a6 * ic; p[7] = a7 * ic;
    }
}

// ---------------------------------------------------------------------------
// Layers 2,3: wide-gather mean + 16->16 transform + ReLU.
// ---------------------------------------------------------------------------
__global__ void k_sage16(const int* __restrict__ rp, const int* __restrict__ csr,
                         const float* __restrict__ inv_cnt, const bf16* __restrict__ h,
                         const float* __restrict__ Wl, const float* __restrict__ bl,
                         const float* __restrict__ Wr,
                         bf16* __restrict__ hout, int n)
{
    __shared__ float sWlT[256], sWrT[256], sb[16];
    __shared__ float sA[16][17], sX[16][17];
    int t = threadIdx.x;
    {
        int j = t & 15, ii = t >> 4;
        sWlT[ii * 16 + j] = Wl[j * 16 + ii];   // LDS addr = t: linear, conflict-free
        sWrT[ii * 16 + j] = Wr[j * 16 + ii];
    }
    if (t < 16) sb[t] = bl[t];
    int grp = t >> 4, f = t & 15;
    int sl = f >> 1, pr = f & 1;
    int i = blockIdx.x * 16 + grp;
    bool valid = i < n;
    const unsigned short* hu = (const unsigned short*)h;
    int r0 = 0, r1 = 0;
    float ic = 0.0f;
    if (valid) { r0 = rp[i]; r1 = rp[i + 1]; ic = inv_cnt[i]; }
    gather8(hu, csr, r0, r1, valid, sl, pr, ic, f, &sA[grp][0]);
    if (valid) sX[grp][f] = __bfloat162float(h[(size_t)i * 16 + f]);
    __syncthreads();
    if (valid) {
        float o = sb[f];
#pragma unroll
        for (int ii = 0; ii < 16; ++ii) {
            o = fmaf(sA[grp][ii], sWlT[ii * 16 + f], o);
            o = fmaf(sX[grp][ii], sWrT[ii * 16 + f], o);
        }
        hout[(size_t)i * 16 + f] = __float2bfloat16(fmaxf(o, 0.0f));
    }
}

// ---------------------------------------------------------------------------
// Layer 4 + decoder + softmax, fused with wide gather.
// ---------------------------------------------------------------------------
__global__ void k_fin(const int* __restrict__ rp, const int* __restrict__ csr,
                      const float* __restrict__ inv_cnt, const bf16* __restrict__ h,
                      const float* __restrict__ W4l, const float* __restrict__ b4l,
                      const float* __restrict__ W4r,
                      const float* __restrict__ Wd1, const float* __restrict__ bd1,
                      const float* __restrict__ Wd2, const float* __restrict__ bd2,
                      float* __restrict__ out, int n)
{
    __shared__ float sW4lT[512], sW4rT[512], sb4[32];
    __shared__ float sWd1T[1024], sbd1[32], sWd2[64], sbd2[2];
    __shared__ float sA[16][17], sX[16][17], sH4[16][33];
    int t = threadIdx.x;
    for (int k = t; k < 512; k += 256) {       // sW4lT[ii*32+j] = W4l[j*16+ii]
        int ii = k >> 5, j = k & 31;
        sW4lT[k] = W4l[j * 16 + ii];
        sW4rT[k] = W4r[j * 16 + ii];
    }
    for (int k = t; k < 1024; k += 256) {      // sWd1T[ii*32+j] = Wd1[j*32+ii]
        int ii = k >> 5, j = k & 31;
        sWd1T[k] = Wd1[j * 32 + ii];
    }
    if (t < 32) { sb4[t] = b4l[t]; sbd1[t] = bd1[t]; }
    if (t < 64) sWd2[t] = Wd2[t];
    if (t < 2)  sbd2[t] = bd2[t];
    int grp = t >> 4, f = t & 15;
    int sl = f >> 1, pr = f & 1;
    int i = blockIdx.x * 16 + grp;
    bool valid = i < n;
    const unsigned short* hu = (const unsigned short*)h;
    int r0 = 0, r1 = 0;
    float ic = 0.0f;
    if (valid) { r0 = rp[i]; r1 = rp[i + 1]; ic = inv_cnt[i]; }
    gather8(hu, csr, r0, r1, valid, sl, pr, ic, f, &sA[grp][0]);
    if (valid) sX[grp][f] = __bfloat162float(h[(size_t)i * 16 + f]);
    __syncthreads();
    float h4a = sb4[f], h4b = sb4[f + 16];
#pragma unroll
    for (int ii = 0; ii < 16; ++ii) {
        float a  = sA[grp][ii];
        float xx = sX[grp][ii];
        h4a = fmaf(a,  sW4lT[ii * 32 + f],      h4a);
        h4b = fmaf(a,  sW4lT[ii * 32 + f + 16], h4b);
        h4a = fmaf(xx, sW4rT[ii * 32 + f],      h4a);
        h4b = fmaf(xx, sW4rT[ii * 32 + f + 16], h4b);
    }
    sH4[grp][f] = h4a;
    sH4[grp][f + 16] = h4b;
    __syncthreads();
    float za = sbd1[f], zb = sbd1[f + 16];
#pragma unroll
    for (int k = 0; k < 32; ++k) {
        float hv = sH4[grp][k];
        za = fmaf(hv, sWd1T[k * 32 + f],      za);
        zb = fmaf(hv, sWd1T[k * 32 + f + 16], zb);
    }
    za = fmaxf(za, 0.0f);
    zb = fmaxf(zb, 0.0f);
    float o0 = za * sWd2[f]      + zb * sWd2[f + 16];
    float o1 = za * sWd2[32 + f] + zb * sWd2[32 + f + 16];
#pragma unroll
    for (int m = 8; m >= 1; m >>= 1) {
        o0 += __shfl_xor(o0, m, 64);
        o1 += __shfl_xor(o1, m, 64);
    }
    if (valid && f == 0) {
        o0 += sbd2[0]; o1 += sbd2[1];
        float mx = fmaxf(o0, o1);
        float e0 = expf(o0 - mx), e1 = expf(o1 - mx);
        float inv = 1.0f / (e0 + e1);
        out[(size_t)2 * i + 0] = e0 * inv;
        out[(size_t)2 * i + 1] = e1 * inv;
    }
}

// ---------------------------------------------------------------------------
extern "C" void kernel_launch(void* const* d_in, const int* in_sizes, int n_in,
                              void* d_out, int out_size, void* d_ws, size_t ws_size,
                              hipStream_t stream)
{
    const float* x  = (const float*)d_in[0];
    const int*   ei = (const int*)d_in[1];
    const int    N  = in_sizes[0];
    const int    E  = in_sizes[1] / 2;
    const int* src = ei;
    const int* dst = ei + E;

    const float* W1l = (const float*)d_in[2];
    const float* b1l = (const float*)d_in[3];
    const float* W1r = (const float*)d_in[4];
    const float* gam = (const float*)d_in[5];
    const float* bet = (const float*)d_in[6];
    const float* mu  = (const float*)d_in[7];
    const float* var = (const float*)d_in[8];
    const float* W2l = (const float*)d_in[9];
    const float* b2l = (const float*)d_in[10];
    const float* W2r = (const float*)d_in[11];
    const float* W3l = (const float*)d_in[12];
    const float* b3l = (const float*)d_in[13];
    const float* W3r = (const float*)d_in[14];
    const float* W4l = (const float*)d_in[15];
    const float* b4l = (const float*)d_in[16];
    const float* W4r = (const float*)d_in[17];
    const float* Wd1 = (const float*)d_in[18];
    const float* bd1 = (const float*)d_in[19];
    const float* Wd2 = (const float*)d_in[20];
    const float* bd2 = (const float*)d_in[21];

    char*  base = (char*)d_ws;
    size_t off  = 0;
    auto alloc = [&](size_t bytes) { size_t p = off; off += (bytes + 63) & ~(size_t)63; return p; };
    float* inv_cnt  = (float*)(base + alloc((size_t)N * 4));
    int*   rp       = (int*)  (base + alloc((size_t)(N + 1) * 4));
    int*   binCnt   = (int*)  (base + alloc(MAXB * 4));
    int*   binStart = (int*)  (base + alloc((MAXB + 1) * 4));
    int*   binCur   = (int*)  (base + alloc(MAXB * 4));
    int*   csr      = (int*)  (base + alloc((size_t)E * 4));
    // stg aliases hA/hB region: stg dead after k_sortbin, hA first written in k_l1g
    size_t regionOff = alloc((size_t)E * 8 > (size_t)N * 64 ? (size_t)E * 8 : (size_t)N * 64);
    iv2*   stg = (iv2*) (base + regionOff);
    bf16*  hA  = (bf16*)(base + regionOff);
    bf16*  hB  = hA + (size_t)N * 16;
    (void)ws_size;

    int nbins   = (N + SPAN - 1) / SPAN;
    int nbPairs = (E + PBE - 1) / PBE;
    int nbN16   = (N + 15) / 16;

    // --- partition edges by dst bin, then per-bin counting sort -> CSR ---
    hipMemsetAsync(binCnt, 0, MAXB * sizeof(int), stream);
    k_hist<<<1024, 256, 0, stream>>>(dst, binCnt, E);
    k_binscan<<<1, 256, 0, stream>>>(binCnt, binStart, binCur, nbins, E);
    k_pairs<<<nbPairs, 256, 0, stream>>>(src, dst, binCur, stg, E);
    k_sortbin<<<nbins, 1024, 0, stream>>>(stg, binStart, rp, inv_cnt, csr, N, nbins);

    // --- gather-based layers ---
    k_l1g<<<nbN16, 256, 0, stream>>>(rp, csr, inv_cnt, x, W1l, b1l, W1r,
                                     gam, bet, mu, var, hA, N);
    k_sage16<<<nbN16, 256, 0, stream>>>(rp, csr, inv_cnt, hA, W2l, b2l, W2r, hB, N);
    k_sage16<<<nbN16, 256, 0, stream>>>(rp, csr, inv_cnt, hB, W3l, b3l, W3r, hA, N);
    k_fin<<<nbN16, 256, 0, stream>>>(rp, csr, inv_cnt, hA, W4l, b4l, W4r,
                                     Wd1, bd1, Wd2, bd2, (float*)d_out, N);
}